// Round 14
// baseline (234.824 us; speedup 1.0000x reference)
//
#include <hip/hip_runtime.h>
#include <hip/hip_bf16.h>
#include <math.h>

#define LSEQ 2048
#define DMODEL 1024
#define DINNER 2048
#define NHEADS 32
#define HEADDIM 64
#define DSTATE 64
#define CONVDIM 2176     // DINNER + 2*DSTATE
#define XBCDT_W 2304     // padded width of (xBC | dt) block
#define FFNHID 3072

typedef float f32x4 __attribute__((ext_vector_type(4)));
typedef __bf16 bf16x8 __attribute__((ext_vector_type(8)));
typedef __hip_bfloat16 bf16;

__device__ __forceinline__ float siluf(float x){ return x / (1.0f + expf(-x)); }

#define GLOAD_LDS16(gp, lp) __builtin_amdgcn_global_load_lds( \
    (const __attribute__((address_space(1))) void*)(gp), \
    (__attribute__((address_space(3))) void*)(lp), 16, 0, 0)

__device__ __forceinline__ float block_reduce_sum_256(float v){
  #pragma unroll
  for (int o = 32; o > 0; o >>= 1) v += __shfl_down(v, o, 64);
  __shared__ float sh[4];
  int lane = threadIdx.x & 63;
  int w = threadIdx.x >> 6;
  if (lane == 0) sh[w] = v;
  __syncthreads();
  return sh[0] + sh[1] + sh[2] + sh[3];
}

__device__ __forceinline__ ushort bf16bits(float f){
  __hip_bfloat16 h = __float2bfloat16(f);
  return *reinterpret_cast<ushort*>(&h);
}
__device__ __forceinline__ float bfu(ushort u){
  union { float f; unsigned int i; } w; w.i = ((unsigned int)u) << 16; return w.f;
}

// XOR-swizzled element index in a 64x64 bf16 LDS tile (8 16B slots/row; slot^=row&7)
__device__ __forceinline__ int swz64(int r, int c){
  return r*64 + ((((c>>3) ^ (r&7)))<<3) + (c&7);
}

// conv4+bias+silu for 8 consecutive cols at (row l, col c0), reading bf16 xbcdt
__device__ __forceinline__ void conv8(
    const bf16* __restrict__ xbcdt, const float* __restrict__ cw,
    const float* __restrict__ cb, int l, int c0, float out[8])
{
  #pragma unroll
  for (int e = 0; e < 8; ++e) out[e] = cb[c0 + e];
  #pragma unroll
  for (int k = 0; k < 4; ++k){
    int t = l + k - 3;
    if (t < 0) continue;
    bf16x8 rv = *(const bf16x8*)(xbcdt + (size_t)t * XBCDT_W + c0);
    #pragma unroll
    for (int e = 0; e < 8; ++e)
      out[e] = fmaf((float)rv[e], cw[(c0 + e)*4 + k], out[e]);
  }
  #pragma unroll
  for (int e = 0; e < 8; ++e) out[e] = siluf(out[e]);
}

// merged: weight casts (blocks [0,15616)) + mix/rms (blocks [15616,17664))
__global__ __launch_bounds__(256) void k_castmix(
    const float* __restrict__ w0, const float* __restrict__ w1,
    const float* __restrict__ w2, const float* __restrict__ w3,
    bf16* __restrict__ d0, bf16* __restrict__ d1,
    bf16* __restrict__ d2, bf16* __restrict__ d3,
    const float* __restrict__ x, const float* __restrict__ x0,
    const float* __restrict__ rm, const float* __restrict__ nw,
    float* __restrict__ xres, bf16* __restrict__ u)
{
  int tid = threadIdx.x;
  if (blockIdx.x < 15616){
    int idx = blockIdx.x * 256 + tid;   // float4 index
    const float* s; bf16* d; int valid;
    if (idx < 1114112)      { s = w0; d = d0; valid = 1089536; }
    else if (idx < 1638400) { idx -= 1114112; s = w1; d = d1; valid = 524288; }
    else if (idx < 3211264) { idx -= 1638400; s = w2; d = d2; valid = 1572864; }
    else                    { idx -= 3211264; s = w3; d = d3; valid = 786432; }
    float4 v = (idx < valid) ? *(const float4*)(s + (size_t)idx * 4)
                             : make_float4(0.f, 0.f, 0.f, 0.f);
    ushort4 r;
    r.x = bf16bits(v.x); r.y = bf16bits(v.y); r.z = bf16bits(v.z); r.w = bf16bits(v.w);
    *(ushort4*)(d + (size_t)idx * 4) = r;
    return;
  }
  int row = blockIdx.x - 15616;
  float4 xv  = ((const float4*)(x  + (size_t)row * DMODEL))[tid];
  float4 x0v = ((const float4*)(x0 + (size_t)row * DMODEL))[tid];
  float4 r0 = ((const float4*)rm)[tid];
  float4 r1 = ((const float4*)(rm + DMODEL))[tid];
  float4 a;
  a.x = r0.x*xv.x + r1.x*x0v.x; a.y = r0.y*xv.y + r1.y*x0v.y;
  a.z = r0.z*xv.z + r1.z*x0v.z; a.w = r0.w*xv.w + r1.w*x0v.w;
  ((float4*)(xres + (size_t)row * DMODEL))[tid] = a;
  float ss = a.x*a.x + a.y*a.y + a.z*a.z + a.w*a.w;
  ss = block_reduce_sum_256(ss);
  float inv = rsqrtf(ss / (float)DMODEL + 1e-6f);
  float4 nv = ((const float4*)nw)[tid];
  ushort4 o;
  o.x = bf16bits(a.x*inv*nv.x); o.y = bf16bits(a.y*inv*nv.y);
  o.z = bf16bits(a.z*inv*nv.z); o.w = bf16bits(a.w*inv*nv.w);
  *(ushort4*)(u + (size_t)row * DMODEL + tid*4) = o;
}

// bijective XCD swizzle for 2D grid (nblk % 8 == 0)
__device__ __forceinline__ void xcdswz2(int &bx, int &by){
  int gx = gridDim.x;
  int nblk = gx * gridDim.y;
  int flat = by * gx + bx;
  flat = (flat & 7) * (nblk >> 3) + (flat >> 3);
  by = flat / gx; bx = flat - by * gx;
}

// ---------- 128x128 bf16 MFMA mainloop, double-buffered, BK=32 ----------
__device__ __forceinline__ void gemm_mainloop128(
    const bf16* __restrict__ A, const bf16* __restrict__ W,
    int ld, int Klen, bf16* As, bf16* Ws, f32x4 acc[4][4])
{
  int tid = threadIdx.x, lane = tid & 63, wid = tid >> 6;
  int wm = (wid >> 1) * 64, wn = (wid & 1) * 64;
  int r16 = lane & 15, g8 = lane >> 4;
  int srow = lane >> 2;
  int scol = ((lane & 3) ^ (srow & 3) ^ ((srow >> 2) & 3)) * 8;
  const bf16* ga0 = A + (size_t)(wid*32 + srow) * ld + scol;
  const bf16* ga1 = ga0 + (size_t)16 * ld;
  const bf16* gw0 = W + (size_t)(wid*32 + srow) * ld + scol;
  const bf16* gw1 = gw0 + (size_t)16 * ld;
  GLOAD_LDS16(ga0, As + wid*1024);
  GLOAD_LDS16(ga1, As + wid*1024 + 512);
  GLOAD_LDS16(gw0, Ws + wid*1024);
  GLOAD_LDS16(gw1, Ws + wid*1024 + 512);
  __syncthreads();
  int cur = 0;
  int s4 = ((r16 & 3) ^ ((r16 >> 2) & 3)) * 8;
  for (int k0 = 0; k0 < Klen; k0 += 32){
    if (k0 + 32 < Klen){
      int nb = (cur ^ 1) * 4096;
      GLOAD_LDS16(ga0 + k0 + 32, As + nb + wid*1024);
      GLOAD_LDS16(ga1 + k0 + 32, As + nb + wid*1024 + 512);
      GLOAD_LDS16(gw0 + k0 + 32, Ws + nb + wid*1024);
      GLOAD_LDS16(gw1 + k0 + 32, Ws + nb + wid*1024 + 512);
    }
    int cb = cur * 4096;
    bf16x8 af[4], bfr[4];
    #pragma unroll
    for (int i = 0; i < 4; ++i)
      af[i] = *(const bf16x8*)(As + cb + (wm + i*16 + r16)*32 + (g8*8 ^ s4));
    #pragma unroll
    for (int j = 0; j < 4; ++j)
      bfr[j] = *(const bf16x8*)(Ws + cb + (wn + j*16 + r16)*32 + (g8*8 ^ s4));
    #pragma unroll
    for (int i = 0; i < 4; ++i)
      #pragma unroll
      for (int j = 0; j < 4; ++j)
        acc[i][j] = __builtin_amdgcn_mfma_f32_16x16x32_bf16(af[i], bfr[j], acc[i][j], 0, 0, 0);
    __syncthreads();
    cur ^= 1;
  }
}

// in_proj: block cols [0,16) -> zbuf bf16 (N=2048), [16,34) -> xbcdt bf16 (N=2304)
__global__ __launch_bounds__(256) void k_gemm_inproj(
    const bf16* __restrict__ A, const bf16* __restrict__ Wfull,
    bf16* __restrict__ zbuf, bf16* __restrict__ xbcdt)
{
  __shared__ __align__(16) bf16 As[2*4096];
  __shared__ __align__(16) bf16 Ws[2*4096];
  int bx = blockIdx.x, by = blockIdx.y;
  xcdswz2(bx, by);
  f32x4 acc[4][4];
  #pragma unroll
  for (int i = 0; i < 4; ++i)
    #pragma unroll
    for (int j = 0; j < 4; ++j) acc[i][j] = (f32x4){0.f,0.f,0.f,0.f};
  gemm_mainloop128(A + (size_t)(by*128)*DMODEL, Wfull + (size_t)(bx*128)*DMODEL,
                   DMODEL, DMODEL, As, Ws, acc);
  int tid = threadIdx.x, lane = tid & 63, wid = tid >> 6;
  int wm = (wid >> 1) * 64, wn = (wid & 1) * 64;
  int r16 = lane & 15, g8 = lane >> 4;
  bf16* Cp; int ldc, col0;
  if (bx < 16){ Cp = zbuf;  ldc = DINNER;  col0 = bx*128; }
  else        { Cp = xbcdt; ldc = XBCDT_W; col0 = (bx-16)*128; }
  #pragma unroll
  for (int i = 0; i < 4; ++i){
    int row = by*128 + wm + i*16 + g8*4;
    #pragma unroll
    for (int j = 0; j < 4; ++j){
      int col = col0 + wn + j*16 + r16;
      #pragma unroll
      for (int r = 0; r < 4; ++r)
        Cp[(size_t)(row + r) * ldc + col] = __float2bfloat16(acc[i][j][r]);
    }
  }
}

// split-K GEMM (4-way): P[z][M][N] bf16 partial over K range [z*Kq, (z+1)*Kq)
__global__ __launch_bounds__(256) void k_gemm_splitk(
    const bf16* __restrict__ A, const bf16* __restrict__ W,
    bf16* __restrict__ P, int Kfull, int Kq, int N)
{
  __shared__ __align__(16) bf16 As[2*4096];
  __shared__ __align__(16) bf16 Ws[2*4096];
  int gx = gridDim.x, gxy = gx * gridDim.y;
  int nblk = gxy * gridDim.z;
  int flat = blockIdx.z * gxy + blockIdx.y * gx + blockIdx.x;
  flat = (flat & 7) * (nblk >> 3) + (flat >> 3);
  int z = flat / gxy; int rem = flat - z * gxy;
  int by = rem / gx, bx = rem - by * gx;
  f32x4 acc[4][4];
  #pragma unroll
  for (int i = 0; i < 4; ++i)
    #pragma unroll
    for (int j = 0; j < 4; ++j) acc[i][j] = (f32x4){0.f,0.f,0.f,0.f};
  gemm_mainloop128(A + (size_t)(by*128)*Kfull + z*Kq,
                   W + (size_t)(bx*128)*Kfull + z*Kq,
                   Kfull, Kq, As, Ws, acc);
  bf16* Pz = P + (size_t)z * LSEQ * N;
  int tid = threadIdx.x, lane = tid & 63, wid = tid >> 6;
  int wm = (wid >> 1) * 64, wn = (wid & 1) * 64;
  int r16 = lane & 15, g8 = lane >> 4;
  #pragma unroll
  for (int i = 0; i < 4; ++i){
    int row = by*128 + wm + i*16 + g8*4;
    #pragma unroll
    for (int j = 0; j < 4; ++j){
      int col = bx*128 + wn + j*16 + r16;
      #pragma unroll
      for (int r = 0; r < 4; ++r)
        Pz[(size_t)(row + r) * N + col] = __float2bfloat16(acc[i][j][r]);
    }
  }
}

// FFN fused: block = 128 rows x 64 act-cols; W LDS tile stacks gate(64)+up(64).
__global__ __launch_bounds__(256) void k_gemm_ffn(
    const bf16* __restrict__ A, const bf16* __restrict__ Wg, const bf16* __restrict__ Wu,
    bf16* __restrict__ act, int K)
{
  __shared__ __align__(16) bf16 As[2*4096];
  __shared__ __align__(16) bf16 Ws[2*4096];
  int bx = blockIdx.x, by = blockIdx.y;
  xcdswz2(bx, by);
  int tid = threadIdx.x, lane = tid & 63, wid = tid >> 6;
  int wm = (wid >> 1) * 64, wc = (wid & 1) * 32;
  int r16 = lane & 15, g8 = lane >> 4;
  int srow = lane >> 2;
  int scol = ((lane & 3) ^ (srow & 3) ^ ((srow >> 2) & 3)) * 8;
  const bf16* ga0 = A + (size_t)(by*128 + wid*32 + srow) * K + scol;
  const bf16* ga1 = ga0 + (size_t)16 * K;
  const bf16* gwsrc = (wid < 2) ? Wg : Wu;
  const bf16* gw0 = gwsrc + (size_t)(bx*64 + (wid & 1)*32 + srow) * K + scol;
  const bf16* gw1 = gw0 + (size_t)16 * K;
  f32x4 accg[4][2], accu[4][2];
  #pragma unroll
  for (int i = 0; i < 4; ++i)
    #pragma unroll
    for (int j = 0; j < 2; ++j){
      accg[i][j] = (f32x4){0.f,0.f,0.f,0.f};
      accu[i][j] = (f32x4){0.f,0.f,0.f,0.f};
    }
  GLOAD_LDS16(ga0, As + wid*1024);
  GLOAD_LDS16(ga1, As + wid*1024 + 512);
  GLOAD_LDS16(gw0, Ws + wid*1024);
  GLOAD_LDS16(gw1, Ws + wid*1024 + 512);
  __syncthreads();
  int cur = 0;
  int s4 = ((r16 & 3) ^ ((r16 >> 2) & 3)) * 8;
  for (int k0 = 0; k0 < K; k0 += 32){
    if (k0 + 32 < K){
      int nb = (cur ^ 1) * 4096;
      GLOAD_LDS16(ga0 + k0 + 32, As + nb + wid*1024);
      GLOAD_LDS16(ga1 + k0 + 32, As + nb + wid*1024 + 512);
      GLOAD_LDS16(gw0 + k0 + 32, Ws + nb + wid*1024);
      GLOAD_LDS16(gw1 + k0 + 32, Ws + nb + wid*1024 + 512);
    }
    int cb = cur * 4096;
    bf16x8 af[4], gf[2], uf[2];
    #pragma unroll
    for (int i = 0; i < 4; ++i)
      af[i] = *(const bf16x8*)(As + cb + (wm + i*16 + r16)*32 + (g8*8 ^ s4));
    #pragma unroll
    for (int j = 0; j < 2; ++j){
      int gr = wc + j*16 + r16;
      int ur = 64 + wc + j*16 + r16;
      gf[j] = *(const bf16x8*)(Ws + cb + gr*32 + (g8*8 ^ s4));
      uf[j] = *(const bf16x8*)(Ws + cb + ur*32 + (g8*8 ^ s4));
    }
    #pragma unroll
    for (int i = 0; i < 4; ++i)
      #pragma unroll
      for (int j = 0; j < 2; ++j){
        accg[i][j] = __builtin_amdgcn_mfma_f32_16x16x32_bf16(af[i], gf[j], accg[i][j], 0, 0, 0);
        accu[i][j] = __builtin_amdgcn_mfma_f32_16x16x32_bf16(af[i], uf[j], accu[i][j], 0, 0, 0);
      }
    __syncthreads();
    cur ^= 1;
  }
  #pragma unroll
  for (int i = 0; i < 4; ++i){
    int row = by*128 + wm + i*16 + g8*4;
    #pragma unroll
    for (int j = 0; j < 2; ++j){
      int col = bx*64 + wc + j*16 + r16;
      #pragma unroll
      for (int r = 0; r < 4; ++r){
        float g = accg[i][j][r], u = accu[i][j][r];
        act[(size_t)(row + r) * FFNHID + col] = __float2bfloat16(siluf(g) * u);
      }
    }
  }
}

// ---- MFMA chunked-SSD pass A (conv fused inline; bf16 T output) ----
__global__ __launch_bounds__(256) void k_scanA(
    const bf16* __restrict__ xbcdt, const float* __restrict__ cw,
    const float* __restrict__ cb, const float* __restrict__ dtb,
    const float* __restrict__ alog, bf16* __restrict__ T, float* __restrict__ ctot)
{
  __shared__ __bf16 sXw[4096];
  __shared__ __bf16 sBt[4096];
  __shared__ float scum[64], swt[64];
  int h = blockIdx.x >> 5, c = blockIdx.x & 31;
  int tid = threadIdx.x, t0 = c * 64;
  if (tid < 64){
    int l = t0 + tid;
    float raw = bfu(*(const ushort*)(xbcdt + (size_t)l * XBCDT_W + CONVDIM + h)) + dtb[h];
    float d = (raw > 20.f) ? raw : log1pf(expf(raw));
    float la = -expf(alog[h]) * d;
    float cum = la;
    #pragma unroll
    for (int o = 1; o < 64; o <<= 1){
      float v = __shfl_up(cum, o, 64);
      if (tid >= o) cum += v;
    }
    scum[tid] = cum;
    swt[tid] = d;   // temporarily store dt
  }
  __syncthreads();
  float Lc = scum[63];
  if (tid < 64)
    swt[tid] = expf(Lc - scum[tid]) * swt[tid];
  __syncthreads();
  for (int idx = tid; idx < 512; idx += 256){
    int j = idx >> 3, n0 = (idx & 7) * 8;
    int l = t0 + j;
    float xv[8], bv[8];
    conv8(xbcdt, cw, cb, l, h * HEADDIM + n0, xv);
    conv8(xbcdt, cw, cb, l, DINNER + n0, bv);
    float wj = swt[j];
    #pragma unroll
    for (int e = 0; e < 8; ++e){
      sXw[swz64(n0 + e, j)] = (__bf16)(xv[e] * wj);
      sBt[swz64(n0 + e, j)] = (__bf16)bv[e];
    }
  }
  __syncthreads();
  int lane = tid & 63, wid = tid >> 6;
  int wr = (wid >> 1) * 32, wc = (wid & 1) * 32;
  int r16 = lane & 15, g8 = lane >> 4;
  f32x4 acc[2][2];
  #pragma unroll
  for (int i = 0; i < 2; ++i)
    #pragma unroll
    for (int j = 0; j < 2; ++j) acc[i][j] = (f32x4){0.f,0.f,0.f,0.f};
  #pragma unroll
  for (int kk = 0; kk < 2; ++kk){
    int ks = kk*4 + g8;
    bf16x8 a[2], b[2];
    #pragma unroll
    for (int i = 0; i < 2; ++i){
      int row = wr + i*16 + r16;
      a[i] = *(const bf16x8*)(sXw + row*64 + ((ks ^ (row&7))<<3));
    }
    #pragma unroll
    for (int j = 0; j < 2; ++j){
      int row = wc + j*16 + r16;
      b[j] = *(const bf16x8*)(sBt + row*64 + ((ks ^ (row&7))<<3));
    }
    #pragma unroll
    for (int i = 0; i < 2; ++i)
      #pragma unroll
      for (int j = 0; j < 2; ++j)
        acc[i][j] = __builtin_amdgcn_mfma_f32_16x16x32_bf16(a[i], b[j], acc[i][j], 0, 0, 0);
  }
  bf16* Tb = T + (size_t)blockIdx.x * 4096;
  #pragma unroll
  for (int i = 0; i < 2; ++i)
    #pragma unroll
    for (int j = 0; j < 2; ++j)
      #pragma unroll
      for (int r = 0; r < 4; ++r){
        int p = wr + i*16 + g8*4 + r, n = wc + j*16 + r16;
        Tb[p*64 + n] = __float2bfloat16(acc[i][j][r]);
      }
  if (tid == 0) ctot[blockIdx.x] = expf(Lc);
}

// pass B: sequential state recurrence over chunks; bf16 storage, fp32 carry
__global__ __launch_bounds__(256) void k_scanB(bf16* __restrict__ T, const float* __restrict__ ctot)
{
  int h = blockIdx.x >> 3, e = blockIdx.x & 7;
  int tid = threadIdx.x;
  size_t off = (size_t)e * 512 + tid * 2;
  float s0 = 0.f, s1 = 0.f;
  for (int c0 = 0; c0 < 32; c0 += 8){
    ushort2 tv[8]; float cts[8];
    #pragma unroll
    for (int q = 0; q < 8; ++q){
      cts[q] = ctot[h * 32 + c0 + q];
      tv[q] = *(const ushort2*)&T[(size_t)(h * 32 + c0 + q) * 4096 + off];
    }
    #pragma unroll
    for (int q = 0; q < 8; ++q){
      size_t base = (size_t)(h * 32 + c0 + q) * 4096 + off;
      ushort2 sv; sv.x = bf16bits(s0); sv.y = bf16bits(s1);
      *(ushort2*)&T[base] = sv;
      s0 = fmaf(cts[q], s0, bfu(tv[q].x));
      s1 = fmaf(cts[q], s1, bfu(tv[q].y));
    }
  }
}

// ---- MFMA chunked-SSD pass C (conv fused inline; bf16 y output) ----
__global__ __launch_bounds__(256) void k_scanC(
    const bf16* __restrict__ xbcdt, const bf16* __restrict__ Sin,
    const float* __restrict__ cw, const float* __restrict__ cb,
    const float* __restrict__ dtb, const float* __restrict__ alog,
    const float* __restrict__ Dp, bf16* __restrict__ y)
{
  __shared__ __bf16 sC[4096];
  __shared__ __bf16 sBS[4096];
  __shared__ __bf16 sXt[4096];
  __shared__ __bf16 sXr[4096];
  __shared__ __bf16 sSb[4096];
  __shared__ float scum[64], sdt[64];
  int h = blockIdx.x >> 5, c = blockIdx.x & 31;
  int tid = threadIdx.x, t0 = c * 64;
  if (tid < 64){
    int l = t0 + tid;
    float raw = bfu(*(const ushort*)(xbcdt + (size_t)l * XBCDT_W + CONVDIM + h)) + dtb[h];
    float d = (raw > 20.f) ? raw : log1pf(expf(raw));
    float la = -expf(alog[h]) * d;
    float cum = la;
    #pragma unroll
    for (int o = 1; o < 64; o <<= 1){
      float v = __shfl_up(cum, o, 64);
      if (tid >= o) cum += v;
    }
    scum[tid] = cum;
    sdt[tid] = d;
  }
  const bf16* Tb = Sin + (size_t)blockIdx.x * 4096;
  for (int idx = tid; idx < 512; idx += 256){
    int j = idx >> 3, n0 = (idx & 7) * 8;
    int l = t0 + j;
    float xv[8], bv[8], cv[8];
    conv8(xbcdt, cw, cb, l, h * HEADDIM + n0, xv);
    conv8(xbcdt, cw, cb, l, DINNER + n0, bv);
    conv8(xbcdt, cw, cb, l, DINNER + DSTATE + n0, cv);
    #pragma unroll
    for (int e = 0; e < 8; ++e){
      sC [swz64(j, n0) + e] = (__bf16)cv[e];
      sBS[swz64(j, n0) + e] = (__bf16)bv[e];
      sXr[swz64(j, n0) + e] = (__bf16)xv[e];
      sXt[swz64(n0 + e, j)] = (__bf16)xv[e];
    }
    *(bf16x8*)(sSb + swz64(j, n0)) = *(const bf16x8*)(Tb + j*64 + n0);
  }
  __syncthreads();
  int lane = tid & 63, wid = tid >> 6;
  int wr = (wid >> 1) * 32, wc = (wid & 1) * 32;
  int r16 = lane & 15, g8 = lane >> 4;
  f32x4 gacc[2][2];
  #pragma unroll
  for (int i = 0; i < 2; ++i)
    #pragma unroll
    for (int j = 0; j < 2; ++j) gacc[i][j] = (f32x4){0.f,0.f,0.f,0.f};
  #pragma unroll
  for (int kk = 0; kk < 2; ++kk){
    int ks = kk*4 + g8;
    bf16x8 a[2], b[2];
    #pragma unroll
    for (int i = 0; i < 2; ++i){
      int row = wr + i*16 + r16;
      a[i] = *(const bf16x8*)(sC + row*64 + ((ks ^ (row&7))<<3));
    }
    #pragma unroll
    for (int j = 0; j < 2; ++j){
      int row = wc + j*16 + r16;
      b[j] = *(const bf16x8*)(sBS + row*64 + ((ks ^ (row&7))<<3));
    }
    #pragma unroll
    for (int i = 0; i < 2; ++i)
      #pragma unroll
      for (int j = 0; j < 2; ++j)
        gacc[i][j] = __builtin_amdgcn_mfma_f32_16x16x32_bf16(a[i], b[j], gacc[i][j], 0, 0, 0);
  }
  __syncthreads();
  #pragma unroll
  for (int i = 0; i < 2; ++i)
    #pragma unroll
    for (int j = 0; j < 2; ++j)
      #pragma unroll
      for (int r = 0; r < 4; ++r){
        int i_ = wr + i*16 + g8*4 + r, j_ = wc + j*16 + r16;
        float v = (j_ <= i_) ? gacc[i][j][r] * expf(scum[i_] - scum[j_]) * sdt[j_] : 0.f;
        sBS[swz64(i_, j_)] = (__bf16)v;
      }
  __syncthreads();
  f32x4 a1[2][2], a2[2][2];
  #pragma unroll
  for (int i = 0; i < 2; ++i)
    #pragma unroll
    for (int j = 0; j < 2; ++j){
      a1[i][j] = (f32x4){0.f,0.f,0.f,0.f};
      a2[i][j] = (f32x4){0.f,0.f,0.f,0.f};
    }
  #pragma unroll
  for (int kk = 0; kk < 2; ++kk){
    int ks = kk*4 + g8;
    bf16x8 sa[2], xa[2], ca[2], sb[2];
    #pragma unroll
    for (int i = 0; i < 2; ++i){
      int row = wr + i*16 + r16;
      sa[i] = *(const bf16x8*)(sBS + row*64 + ((ks ^ (row&7))<<3));
      ca[i] = *(const bf16x8*)(sC  + row*64 + ((ks ^ (row&7))<<3));
    }
    #pragma unroll
    for (int j = 0; j < 2; ++j){
      int row = wc + j*16 + r16;
      xa[j] = *(const bf16x8*)(sXt + row*64 + ((ks ^ (row&7))<<3));
      sb[j] = *(const bf16x8*)(sSb + row*64 + ((ks ^ (row&7))<<3));
    }
    #pragma unroll
    for (int i = 0; i < 2; ++i)
      #pragma unroll
      for (int j = 0; j < 2; ++j){
        a1[i][j] = __builtin_amdgcn_mfma_f32_16x16x32_bf16(sa[i], xa[j], a1[i][j], 0, 0, 0);
        a2[i][j] = __builtin_amdgcn_mfma_f32_16x16x32_bf16(ca[i], sb[j], a2[i][j], 0, 0, 0);
      }
  }
  float Dh = Dp[h];
  #pragma unroll
  for (int i = 0; i < 2; ++i)
    #pragma unroll
    for (int r = 0; r < 4; ++r){
      int i_ = wr + i*16 + g8*4 + r;
      float wi = expf(scum[i_]);
      #pragma unroll
      for (int j = 0; j < 2; ++j){
        int p_ = wc + j*16 + r16;
        float xv = (float)sXr[swz64(i_, p_)];
        y[(size_t)(t0 + i_) * DINNER + h * HEADDIM + p_] =
            __float2bfloat16(a1[i][j][r] + wi * a2[i][j][r] + Dh * xv);
      }
    }
}

// yn = bf16(rms(y * silu(z)) * mnorm_w)   (y, z bf16)
__global__ __launch_bounds__(256) void k_gate_rms(
    const bf16* __restrict__ y, const bf16* __restrict__ zbuf,
    const float* __restrict__ mw, bf16* __restrict__ yn)
{
  int row = blockIdx.x, tid = threadIdx.x;
  bf16x8 yv = *(const bf16x8*)(y    + (size_t)row * DINNER + tid*8);
  bf16x8 zv = *(const bf16x8*)(zbuf + (size_t)row * DINNER + tid*8);
  float g[8]; float ss = 0.f;
  #pragma unroll
  for (int e = 0; e < 8; ++e){
    float gv = (float)yv[e] * siluf((float)zv[e]);
    g[e] = gv; ss += gv * gv;
  }
  ss = block_reduce_sum_256(ss);
  float inv = rsqrtf(ss / (float)DINNER + 1e-6f);
  float4 m0 = ((const float4*)mw)[tid*2];
  float4 m1 = ((const float4*)mw)[tid*2 + 1];
  const float* mp = (const float*)&m0;
  bf16x8 o;
  #pragma unroll
  for (int e = 0; e < 4; ++e) o[e] = (__bf16)(g[e] * inv * mp[e]);
  mp = (const float*)&m1;
  #pragma unroll
  for (int e = 0; e < 4; ++e) o[4+e] = (__bf16)(g[4+e] * inv * mp[e]);
  *(bf16x8*)(yn + (size_t)row * DINNER + tid*8) = o;
}

// x2 = xres + ssm_scale*(y0+y1+y2+y3) ; hb = bf16(rms(x2)*ffn_norm_w)  (yoP bf16)
__global__ __launch_bounds__(256) void k_res_rms(
    const float* __restrict__ xres, const bf16* __restrict__ yoP,
    const float* __restrict__ scale, const float* __restrict__ nw,
    float* __restrict__ x2, bf16* __restrict__ hb)
{
  int row = blockIdx.x, tid = threadIdx.x;
  const size_t PS = (size_t)LSEQ * DMODEL;
  float4 xv = ((const float4*)(xres + (size_t)row * DMODEL))[tid];
  ushort4 p0 = *(const ushort4*)(yoP          + (size_t)row * DMODEL + tid*4);
  ushort4 p1 = *(const ushort4*)(yoP +   PS   + (size_t)row * DMODEL + tid*4);
  ushort4 p2 = *(const ushort4*)(yoP + 2*PS   + (size_t)row * DMODEL + tid*4);
  ushort4 p3 = *(const ushort4*)(yoP + 3*PS   + (size_t)row * DMODEL + tid*4);
  float4 sv = ((const float4*)scale)[tid];
  float4 a;
  a.x = xv.x + sv.x*(bfu(p0.x)+bfu(p1.x)+bfu(p2.x)+bfu(p3.x));
  a.y = xv.y + sv.y*(bfu(p0.y)+bfu(p1.y)+bfu(p2.y)+bfu(p3.y));
  a.z = xv.z + sv.z*(bfu(p0.z)+bfu(p1.z)+bfu(p2.z)+bfu(p3.z));
  a.w = xv.w + sv.w*(bfu(p0.w)+bfu(p1.w)+bfu(p2.w)+bfu(p3.w));
  ((float4*)(x2 + (size_t)row * DMODEL))[tid] = a;
  float ss = a.x*a.x + a.y*a.y + a.z*a.z + a.w*a.w;
  ss = block_reduce_sum_256(ss);
  float inv = rsqrtf(ss / (float)DMODEL + 1e-6f);
  float4 nv = ((const float4*)nw)[tid];
  ushort4 o;
  o.x = bf16bits(a.x*inv*nv.x); o.y = bf16bits(a.y*inv*nv.y);
  o.z = bf16bits(a.z*inv*nv.z); o.w = bf16bits(a.w*inv*nv.w);
  *(ushort4*)(hb + (size_t)row * DMODEL + tid*4) = o;
}

// out = x2 + mscale*(d0+d1+d2+d3)   (dP bf16)
__global__ __launch_bounds__(256) void k_final(
    const float* __restrict__ x2, const bf16* __restrict__ dP,
    const float* __restrict__ mscale, float* __restrict__ out)
{
  int i4 = blockIdx.x * 256 + threadIdx.x;
  const size_t PS = (size_t)LSEQ * DMODEL;
  float4 xv = ((const float4*)x2)[i4];
  ushort4 p0 = *(const ushort4*)(dP        + (size_t)i4*4);
  ushort4 p1 = *(const ushort4*)(dP + PS   + (size_t)i4*4);
  ushort4 p2 = *(const ushort4*)(dP + 2*PS + (size_t)i4*4);
  ushort4 p3 = *(const ushort4*)(dP + 3*PS + (size_t)i4*4);
  float4 mv = ((const float4*)mscale)[i4 & 255];
  float4 o;
  o.x = xv.x + mv.x*(bfu(p0.x)+bfu(p1.x)+bfu(p2.x)+bfu(p3.x));
  o.y = xv.y + mv.y*(bfu(p0.y)+bfu(p1.y)+bfu(p2.y)+bfu(p3.y));
  o.z = xv.z + mv.z*(bfu(p0.z)+bfu(p1.z)+bfu(p2.z)+bfu(p3.z));
  o.w = xv.w + mv.w*(bfu(p0.w)+bfu(p1.w)+bfu(p2.w)+bfu(p3.w));
  ((float4*)out)[i4] = o;
}

extern "C" void kernel_launch(void* const* d_in, const int* in_sizes, int n_in,
                              void* d_out, int out_size, void* d_ws, size_t ws_size,
                              hipStream_t stream)
{
  const float* x      = (const float*)d_in[0];
  const float* x0     = (const float*)d_in[1];
  const float* rm     = (const float*)d_in[3];
  const float* sscale = (const float*)d_in[4];
  const float* mscale = (const float*)d_in[5];
  const float* snw    = (const float*)d_in[6];
  const float* fnw    = (const float*)d_in[7];
  const float* win    = (const float*)d_in[8];
  const float* cw     = (const float*)d_in[9];
  const float* cb     = (const float*)d_in[10];
  const float* dtb    = (const float*)d_in[11];
  const float* alog   = (const float*)d_in[12];
  const float* Dp     = (const float*)d_in[13];
  const float* mnw    = (const float*)d_in[14];
  const float* wout   = (const float*)d_in[15];
  const float* wgu    = (const float*)d_in[16];
  const float* wdn    = (const float*)d_in[17];
  float* out = (float*)d_out;

  // Workspace (MiB offsets), lifetime-overlapped (R13 skeleton; xbc/dtv/lav gone):
  //  [0,4) woutb ; [4,16) wgub ; [16,22) wdnb ; [22,30) xres ; [30,39) winb
  //  [39,43) u bf16 -> hb bf16
  //  [43,51) zbuf bf16 (dead after gate_rms) -> x2 fp32
  //  [59,69) xbcdt bf16 (alive through scanC) ; yb bf16 [69,77) ; yoP bf16 [59,75)* ;
  //   act bf16 [59,71) ; dP bf16 [71,87)
  //   (*yoP written after xbcdt dead (scanC done), before act)
  //  [95,103) T/Sin bf16 ; yn bf16 [87,95)
  //  [112] ctot
  const size_t MB = 1024ull * 1024ull;
  char* ws = (char*)d_ws;
  bf16*  woutb = (bf16*) (ws + 0*MB);
  bf16*  wgub  = (bf16*) (ws + 4*MB);
  bf16*  wdnb  = (bf16*) (ws + 16*MB);
  float* xres  = (float*)(ws + 22*MB);
  bf16*  winb  = (bf16*) (ws + 30*MB);
  bf16*  u     = (bf16*) (ws + 39*MB);
  bf16*  hb    = (bf16*) (ws + 39*MB);
  bf16*  zbuf  = (bf16*) (ws + 43*MB);
  float* x2    = (float*)(ws + 43*MB);
  bf16*  xbcdt = (bf16*) (ws + 59*MB);
  bf16*  yoP   = (bf16*) (ws + 59*MB);
  bf16*  act   = (bf16*) (ws + 59*MB);
  bf16*  yb    = (bf16*) (ws + 69*MB);
  bf16*  dP    = (bf16*) (ws + 71*MB);
  bf16*  yn    = (bf16*) (ws + 87*MB);
  bf16*  T     = (bf16*) (ws + 95*MB);
  float* ctot  = (float*)(ws + 112*MB);

  dim3 blk(256);
  k_castmix<<<17664, blk, 0, stream>>>(win, wout, wgu, wdn, winb, woutb, wgub, wdnb,
                                       x, x0, rm, snw, xres, u);
  k_gemm_inproj<<<dim3(34,16), blk, 0, stream>>>(u, winb, zbuf, xbcdt);
  k_scanA<<<NHEADS*32, blk, 0, stream>>>(xbcdt, cw, cb, dtb, alog, T, ctot);
  k_scanB<<<NHEADS*8, blk, 0, stream>>>(T, ctot);
  k_scanC<<<NHEADS*32, blk, 0, stream>>>(xbcdt, T, cw, cb, dtb, alog, Dp, yb);
  k_gate_rms<<<LSEQ, blk, 0, stream>>>(yb, zbuf, mnw, yn);
  k_gemm_splitk<<<dim3(8,16,4), blk, 0, stream>>>(yn, woutb, yoP, DINNER, DINNER/4, DMODEL);
  k_res_rms<<<LSEQ, blk, 0, stream>>>(xres, yoP, sscale, fnw, x2, hb);
  k_gemm_ffn<<<dim3(48,16), blk, 0, stream>>>(hb, wgub, wgub + (size_t)FFNHID*DMODEL, act, DMODEL);
  k_gemm_splitk<<<dim3(8,16,4), blk, 0, stream>>>(act, wdnb, dP, FFNHID, FFNHID/4, DMODEL);
  k_final<<<2048, blk, 0, stream>>>(x2, dP, mscale, out);
}

// Round 15
// 189.331 us; speedup vs baseline: 1.2403x; 1.2403x over previous
//
#include <hip/hip_runtime.h>
#include <hip/hip_bf16.h>
#include <math.h>

#define LSEQ 2048
#define DMODEL 1024
#define DINNER 2048
#define NHEADS 32
#define HEADDIM 64
#define DSTATE 64
#define CONVDIM 2176     // DINNER + 2*DSTATE
#define XBCDT_W 2304     // padded width of (xBC | dt) block
#define FFNHID 3072

typedef float f32x4 __attribute__((ext_vector_type(4)));
typedef __bf16 bf16x8 __attribute__((ext_vector_type(8)));
typedef __hip_bfloat16 bf16;

__device__ __forceinline__ float siluf(float x){ return x / (1.0f + expf(-x)); }

#define GLOAD_LDS16(gp, lp) __builtin_amdgcn_global_load_lds( \
    (const __attribute__((address_space(1))) void*)(gp), \
    (__attribute__((address_space(3))) void*)(lp), 16, 0, 0)

__device__ __forceinline__ float block_reduce_sum_256(float v){
  #pragma unroll
  for (int o = 32; o > 0; o >>= 1) v += __shfl_down(v, o, 64);
  __shared__ float sh[4];
  int lane = threadIdx.x & 63;
  int w = threadIdx.x >> 6;
  if (lane == 0) sh[w] = v;
  __syncthreads();
  return sh[0] + sh[1] + sh[2] + sh[3];
}

__device__ __forceinline__ ushort bf16bits(float f){
  __hip_bfloat16 h = __float2bfloat16(f);
  return *reinterpret_cast<ushort*>(&h);
}
__device__ __forceinline__ float bfu(ushort u){
  union { float f; unsigned int i; } w; w.i = ((unsigned int)u) << 16; return w.f;
}

// XOR-swizzled element index in a 64x64 bf16 LDS tile (8 16B slots/row; slot^=row&7)
__device__ __forceinline__ int swz64(int r, int c){
  return r*64 + ((((c>>3) ^ (r&7)))<<3) + (c&7);
}

// merged: weight casts (blocks [0,15616)) + mix/rms (blocks [15616,17664))
__global__ __launch_bounds__(256) void k_castmix(
    const float* __restrict__ w0, const float* __restrict__ w1,
    const float* __restrict__ w2, const float* __restrict__ w3,
    bf16* __restrict__ d0, bf16* __restrict__ d1,
    bf16* __restrict__ d2, bf16* __restrict__ d3,
    const float* __restrict__ x, const float* __restrict__ x0,
    const float* __restrict__ rm, const float* __restrict__ nw,
    float* __restrict__ xres, bf16* __restrict__ u)
{
  int tid = threadIdx.x;
  if (blockIdx.x < 15616){
    int idx = blockIdx.x * 256 + tid;   // float4 index
    const float* s; bf16* d; int valid;
    if (idx < 1114112)      { s = w0; d = d0; valid = 1089536; }
    else if (idx < 1638400) { idx -= 1114112; s = w1; d = d1; valid = 524288; }
    else if (idx < 3211264) { idx -= 1638400; s = w2; d = d2; valid = 1572864; }
    else                    { idx -= 3211264; s = w3; d = d3; valid = 786432; }
    float4 v = (idx < valid) ? *(const float4*)(s + (size_t)idx * 4)
                             : make_float4(0.f, 0.f, 0.f, 0.f);
    ushort4 r;
    r.x = bf16bits(v.x); r.y = bf16bits(v.y); r.z = bf16bits(v.z); r.w = bf16bits(v.w);
    *(ushort4*)(d + (size_t)idx * 4) = r;
    return;
  }
  int row = blockIdx.x - 15616;
  float4 xv  = ((const float4*)(x  + (size_t)row * DMODEL))[tid];
  float4 x0v = ((const float4*)(x0 + (size_t)row * DMODEL))[tid];
  float4 r0 = ((const float4*)rm)[tid];
  float4 r1 = ((const float4*)(rm + DMODEL))[tid];
  float4 a;
  a.x = r0.x*xv.x + r1.x*x0v.x; a.y = r0.y*xv.y + r1.y*x0v.y;
  a.z = r0.z*xv.z + r1.z*x0v.z; a.w = r0.w*xv.w + r1.w*x0v.w;
  ((float4*)(xres + (size_t)row * DMODEL))[tid] = a;
  float ss = a.x*a.x + a.y*a.y + a.z*a.z + a.w*a.w;
  ss = block_reduce_sum_256(ss);
  float inv = rsqrtf(ss / (float)DMODEL + 1e-6f);
  float4 nv = ((const float4*)nw)[tid];
  ushort4 o;
  o.x = bf16bits(a.x*inv*nv.x); o.y = bf16bits(a.y*inv*nv.y);
  o.z = bf16bits(a.z*inv*nv.z); o.w = bf16bits(a.w*inv*nv.w);
  *(ushort4*)(u + (size_t)row * DMODEL + tid*4) = o;
}

// bijective XCD swizzle for 2D grid (nblk % 8 == 0)
__device__ __forceinline__ void xcdswz2(int &bx, int &by){
  int gx = gridDim.x;
  int nblk = gx * gridDim.y;
  int flat = by * gx + bx;
  flat = (flat & 7) * (nblk >> 3) + (flat >> 3);
  by = flat / gx; bx = flat - by * gx;
}

// ---------- 128x128 bf16 MFMA mainloop, double-buffered, BK=32 ----------
__device__ __forceinline__ void gemm_mainloop128(
    const bf16* __restrict__ A, const bf16* __restrict__ W,
    int ld, int Klen, bf16* As, bf16* Ws, f32x4 acc[4][4])
{
  int tid = threadIdx.x, lane = tid & 63, wid = tid >> 6;
  int wm = (wid >> 1) * 64, wn = (wid & 1) * 64;
  int r16 = lane & 15, g8 = lane >> 4;
  int srow = lane >> 2;
  int scol = ((lane & 3) ^ (srow & 3) ^ ((srow >> 2) & 3)) * 8;
  const bf16* ga0 = A + (size_t)(wid*32 + srow) * ld + scol;
  const bf16* ga1 = ga0 + (size_t)16 * ld;
  const bf16* gw0 = W + (size_t)(wid*32 + srow) * ld + scol;
  const bf16* gw1 = gw0 + (size_t)16 * ld;
  GLOAD_LDS16(ga0, As + wid*1024);
  GLOAD_LDS16(ga1, As + wid*1024 + 512);
  GLOAD_LDS16(gw0, Ws + wid*1024);
  GLOAD_LDS16(gw1, Ws + wid*1024 + 512);
  __syncthreads();
  int cur = 0;
  int s4 = ((r16 & 3) ^ ((r16 >> 2) & 3)) * 8;
  for (int k0 = 0; k0 < Klen; k0 += 32){
    if (k0 + 32 < Klen){
      int nb = (cur ^ 1) * 4096;
      GLOAD_LDS16(ga0 + k0 + 32, As + nb + wid*1024);
      GLOAD_LDS16(ga1 + k0 + 32, As + nb + wid*1024 + 512);
      GLOAD_LDS16(gw0 + k0 + 32, Ws + nb + wid*1024);
      GLOAD_LDS16(gw1 + k0 + 32, Ws + nb + wid*1024 + 512);
    }
    int cb = cur * 4096;
    bf16x8 af[4], bfr[4];
    #pragma unroll
    for (int i = 0; i < 4; ++i)
      af[i] = *(const bf16x8*)(As + cb + (wm + i*16 + r16)*32 + (g8*8 ^ s4));
    #pragma unroll
    for (int j = 0; j < 4; ++j)
      bfr[j] = *(const bf16x8*)(Ws + cb + (wn + j*16 + r16)*32 + (g8*8 ^ s4));
    #pragma unroll
    for (int i = 0; i < 4; ++i)
      #pragma unroll
      for (int j = 0; j < 4; ++j)
        acc[i][j] = __builtin_amdgcn_mfma_f32_16x16x32_bf16(af[i], bfr[j], acc[i][j], 0, 0, 0);
    __syncthreads();
    cur ^= 1;
  }
}

// in_proj: block cols [0,16) -> zbuf bf16 (N=2048), [16,34) -> xbcdt bf16 (N=2304)
__global__ __launch_bounds__(256) void k_gemm_inproj(
    const bf16* __restrict__ A, const bf16* __restrict__ Wfull,
    bf16* __restrict__ zbuf, bf16* __restrict__ xbcdt)
{
  __shared__ __align__(16) bf16 As[2*4096];
  __shared__ __align__(16) bf16 Ws[2*4096];
  int bx = blockIdx.x, by = blockIdx.y;
  xcdswz2(bx, by);
  f32x4 acc[4][4];
  #pragma unroll
  for (int i = 0; i < 4; ++i)
    #pragma unroll
    for (int j = 0; j < 4; ++j) acc[i][j] = (f32x4){0.f,0.f,0.f,0.f};
  gemm_mainloop128(A + (size_t)(by*128)*DMODEL, Wfull + (size_t)(bx*128)*DMODEL,
                   DMODEL, DMODEL, As, Ws, acc);
  int tid = threadIdx.x, lane = tid & 63, wid = tid >> 6;
  int wm = (wid >> 1) * 64, wn = (wid & 1) * 64;
  int r16 = lane & 15, g8 = lane >> 4;
  bf16* Cp; int ldc, col0;
  if (bx < 16){ Cp = zbuf;  ldc = DINNER;  col0 = bx*128; }
  else        { Cp = xbcdt; ldc = XBCDT_W; col0 = (bx-16)*128; }
  #pragma unroll
  for (int i = 0; i < 4; ++i){
    int row = by*128 + wm + i*16 + g8*4;
    #pragma unroll
    for (int j = 0; j < 4; ++j){
      int col = col0 + wn + j*16 + r16;
      #pragma unroll
      for (int r = 0; r < 4; ++r)
        Cp[(size_t)(row + r) * ldc + col] = __float2bfloat16(acc[i][j][r]);
    }
  }
}

// split-K GEMM (4-way): P[z][M][N] bf16 partial over K range [z*Kq, (z+1)*Kq)
__global__ __launch_bounds__(256) void k_gemm_splitk(
    const bf16* __restrict__ A, const bf16* __restrict__ W,
    bf16* __restrict__ P, int Kfull, int Kq, int N)
{
  __shared__ __align__(16) bf16 As[2*4096];
  __shared__ __align__(16) bf16 Ws[2*4096];
  int gx = gridDim.x, gxy = gx * gridDim.y;
  int nblk = gxy * gridDim.z;
  int flat = blockIdx.z * gxy + blockIdx.y * gx + blockIdx.x;
  flat = (flat & 7) * (nblk >> 3) + (flat >> 3);
  int z = flat / gxy; int rem = flat - z * gxy;
  int by = rem / gx, bx = rem - by * gx;
  f32x4 acc[4][4];
  #pragma unroll
  for (int i = 0; i < 4; ++i)
    #pragma unroll
    for (int j = 0; j < 4; ++j) acc[i][j] = (f32x4){0.f,0.f,0.f,0.f};
  gemm_mainloop128(A + (size_t)(by*128)*Kfull + z*Kq,
                   W + (size_t)(bx*128)*Kfull + z*Kq,
                   Kfull, Kq, As, Ws, acc);
  bf16* Pz = P + (size_t)z * LSEQ * N;
  int tid = threadIdx.x, lane = tid & 63, wid = tid >> 6;
  int wm = (wid >> 1) * 64, wn = (wid & 1) * 64;
  int r16 = lane & 15, g8 = lane >> 4;
  #pragma unroll
  for (int i = 0; i < 4; ++i){
    int row = by*128 + wm + i*16 + g8*4;
    #pragma unroll
    for (int j = 0; j < 4; ++j){
      int col = bx*128 + wn + j*16 + r16;
      #pragma unroll
      for (int r = 0; r < 4; ++r)
        Pz[(size_t)(row + r) * N + col] = __float2bfloat16(acc[i][j][r]);
    }
  }
}

// FFN fused: block = 128 rows x 64 act-cols; W LDS tile stacks gate(64)+up(64).
__global__ __launch_bounds__(256) void k_gemm_ffn(
    const bf16* __restrict__ A, const bf16* __restrict__ Wg, const bf16* __restrict__ Wu,
    bf16* __restrict__ act, int K)
{
  __shared__ __align__(16) bf16 As[2*4096];
  __shared__ __align__(16) bf16 Ws[2*4096];
  int bx = blockIdx.x, by = blockIdx.y;
  xcdswz2(bx, by);
  int tid = threadIdx.x, lane = tid & 63, wid = tid >> 6;
  int wm = (wid >> 1) * 64, wc = (wid & 1) * 32;
  int r16 = lane & 15, g8 = lane >> 4;
  int srow = lane >> 2;
  int scol = ((lane & 3) ^ (srow & 3) ^ ((srow >> 2) & 3)) * 8;
  const bf16* ga0 = A + (size_t)(by*128 + wid*32 + srow) * K + scol;
  const bf16* ga1 = ga0 + (size_t)16 * K;
  const bf16* gwsrc = (wid < 2) ? Wg : Wu;
  const bf16* gw0 = gwsrc + (size_t)(bx*64 + (wid & 1)*32 + srow) * K + scol;
  const bf16* gw1 = gw0 + (size_t)16 * K;
  f32x4 accg[4][2], accu[4][2];
  #pragma unroll
  for (int i = 0; i < 4; ++i)
    #pragma unroll
    for (int j = 0; j < 2; ++j){
      accg[i][j] = (f32x4){0.f,0.f,0.f,0.f};
      accu[i][j] = (f32x4){0.f,0.f,0.f,0.f};
    }
  GLOAD_LDS16(ga0, As + wid*1024);
  GLOAD_LDS16(ga1, As + wid*1024 + 512);
  GLOAD_LDS16(gw0, Ws + wid*1024);
  GLOAD_LDS16(gw1, Ws + wid*1024 + 512);
  __syncthreads();
  int cur = 0;
  int s4 = ((r16 & 3) ^ ((r16 >> 2) & 3)) * 8;
  for (int k0 = 0; k0 < K; k0 += 32){
    if (k0 + 32 < K){
      int nb = (cur ^ 1) * 4096;
      GLOAD_LDS16(ga0 + k0 + 32, As + nb + wid*1024);
      GLOAD_LDS16(ga1 + k0 + 32, As + nb + wid*1024 + 512);
      GLOAD_LDS16(gw0 + k0 + 32, Ws + nb + wid*1024);
      GLOAD_LDS16(gw1 + k0 + 32, Ws + nb + wid*1024 + 512);
    }
    int cb = cur * 4096;
    bf16x8 af[4], gf[2], uf[2];
    #pragma unroll
    for (int i = 0; i < 4; ++i)
      af[i] = *(const bf16x8*)(As + cb + (wm + i*16 + r16)*32 + (g8*8 ^ s4));
    #pragma unroll
    for (int j = 0; j < 2; ++j){
      int gr = wc + j*16 + r16;
      int ur = 64 + wc + j*16 + r16;
      gf[j] = *(const bf16x8*)(Ws + cb + gr*32 + (g8*8 ^ s4));
      uf[j] = *(const bf16x8*)(Ws + cb + ur*32 + (g8*8 ^ s4));
    }
    #pragma unroll
    for (int i = 0; i < 4; ++i)
      #pragma unroll
      for (int j = 0; j < 2; ++j){
        accg[i][j] = __builtin_amdgcn_mfma_f32_16x16x32_bf16(af[i], gf[j], accg[i][j], 0, 0, 0);
        accu[i][j] = __builtin_amdgcn_mfma_f32_16x16x32_bf16(af[i], uf[j], accu[i][j], 0, 0, 0);
      }
    __syncthreads();
    cur ^= 1;
  }
  #pragma unroll
  for (int i = 0; i < 4; ++i){
    int row = by*128 + wm + i*16 + g8*4;
    #pragma unroll
    for (int j = 0; j < 2; ++j){
      int col = bx*64 + wc + j*16 + r16;
      #pragma unroll
      for (int r = 0; r < 4; ++r){
        float g = accg[i][j][r], u = accu[i][j][r];
        act[(size_t)(row + r) * FFNHID + col] = __float2bfloat16(siluf(g) * u);
      }
    }
  }
}

// fused conv4+silu (4 channels/thread, bf16 in/out) + dt path (4 heads/thread)
__global__ __launch_bounds__(256) void k_convdt(
    const bf16* __restrict__ xbcdt, const float* __restrict__ cw,
    const float* __restrict__ cb, const float* __restrict__ dtb,
    const float* __restrict__ alog, bf16* __restrict__ xbc,
    float* __restrict__ dtv, float* __restrict__ lav)
{
  int idx = blockIdx.x * 256 + threadIdx.x;   // LSEQ * 552 jobs
  int l = idx / 552, q = idx - l * 552;
  if (l >= LSEQ) return;
  if (q < 544){
    int c = q * 4;
    float4 bv = *(const float4*)(cb + c);
    float acc0 = bv.x, acc1 = bv.y, acc2 = bv.z, acc3 = bv.w;
    float4 w0 = *(const float4*)(cw + (size_t)(c+0)*4);
    float4 w1 = *(const float4*)(cw + (size_t)(c+1)*4);
    float4 w2 = *(const float4*)(cw + (size_t)(c+2)*4);
    float4 w3 = *(const float4*)(cw + (size_t)(c+3)*4);
    const float* w0p = (const float*)&w0;
    const float* w1p = (const float*)&w1;
    const float* w2p = (const float*)&w2;
    const float* w3p = (const float*)&w3;
    #pragma unroll
    for (int k = 0; k < 4; ++k){
      int t = l + k - 3;
      if (t < 0) continue;
      ushort4 rv = *(const ushort4*)(xbcdt + (size_t)t * XBCDT_W + c);
      acc0 = fmaf(bfu(rv.x), w0p[k], acc0);
      acc1 = fmaf(bfu(rv.y), w1p[k], acc1);
      acc2 = fmaf(bfu(rv.z), w2p[k], acc2);
      acc3 = fmaf(bfu(rv.w), w3p[k], acc3);
    }
    ushort4 o;
    o.x = bf16bits(siluf(acc0)); o.y = bf16bits(siluf(acc1));
    o.z = bf16bits(siluf(acc2)); o.w = bf16bits(siluf(acc3));
    *(ushort4*)(xbc + (size_t)l * CONVDIM + c) = o;
  } else {
    int h0 = (q - 544) * 4;
    ushort4 rv = *(const ushort4*)(xbcdt + (size_t)l * XBCDT_W + CONVDIM + h0);
    float raws[4] = { bfu(rv.x), bfu(rv.y), bfu(rv.z), bfu(rv.w) };
    #pragma unroll
    for (int i = 0; i < 4; ++i){
      float raw = raws[i] + dtb[h0 + i];
      float d = (raw > 20.f) ? raw : log1pf(expf(raw));
      dtv[l * NHEADS + h0 + i] = d;
      lav[l * NHEADS + h0 + i] = -expf(alog[h0 + i]) * d;
    }
  }
}

// ---- MFMA chunked-SSD pass A (bf16 xbc input, bf16 T output) ----
__global__ __launch_bounds__(256) void k_scanA(
    const bf16* __restrict__ xbc, const float* __restrict__ dtv,
    const float* __restrict__ lav, bf16* __restrict__ T, float* __restrict__ ctot)
{
  __shared__ __bf16 sXw[4096];
  __shared__ __bf16 sBt[4096];
  __shared__ float scum[64], swt[64];
  int h = blockIdx.x >> 5, c = blockIdx.x & 31;
  int tid = threadIdx.x, t0 = c * 64;
  if (tid < 64){
    float cum = lav[(size_t)(t0 + tid) * NHEADS + h];
    #pragma unroll
    for (int o = 1; o < 64; o <<= 1){
      float v = __shfl_up(cum, o, 64);
      if (tid >= o) cum += v;
    }
    scum[tid] = cum;
  }
  __syncthreads();
  float Lc = scum[63];
  if (tid < 64)
    swt[tid] = expf(Lc - scum[tid]) * dtv[(size_t)(t0 + tid) * NHEADS + h];
  __syncthreads();
  for (int idx = tid; idx < 512; idx += 256){
    int j = idx >> 3, n0 = (idx & 7) * 8;
    const bf16* rb = xbc + (size_t)(t0 + j) * CONVDIM;
    bf16x8 x8 = *(const bf16x8*)(rb + h * HEADDIM + n0);
    bf16x8 b8 = *(const bf16x8*)(rb + DINNER + n0);
    float wj = swt[j];
    #pragma unroll
    for (int e = 0; e < 8; ++e){
      sXw[swz64(n0 + e, j)] = (__bf16)((float)x8[e] * wj);
      sBt[swz64(n0 + e, j)] = b8[e];
    }
  }
  __syncthreads();
  int lane = tid & 63, wid = tid >> 6;
  int wr = (wid >> 1) * 32, wc = (wid & 1) * 32;
  int r16 = lane & 15, g8 = lane >> 4;
  f32x4 acc[2][2];
  #pragma unroll
  for (int i = 0; i < 2; ++i)
    #pragma unroll
    for (int j = 0; j < 2; ++j) acc[i][j] = (f32x4){0.f,0.f,0.f,0.f};
  #pragma unroll
  for (int kk = 0; kk < 2; ++kk){
    int ks = kk*4 + g8;
    bf16x8 a[2], b[2];
    #pragma unroll
    for (int i = 0; i < 2; ++i){
      int row = wr + i*16 + r16;
      a[i] = *(const bf16x8*)(sXw + row*64 + ((ks ^ (row&7))<<3));
    }
    #pragma unroll
    for (int j = 0; j < 2; ++j){
      int row = wc + j*16 + r16;
      b[j] = *(const bf16x8*)(sBt + row*64 + ((ks ^ (row&7))<<3));
    }
    #pragma unroll
    for (int i = 0; i < 2; ++i)
      #pragma unroll
      for (int j = 0; j < 2; ++j)
        acc[i][j] = __builtin_amdgcn_mfma_f32_16x16x32_bf16(a[i], b[j], acc[i][j], 0, 0, 0);
  }
  bf16* Tb = T + (size_t)blockIdx.x * 4096;
  #pragma unroll
  for (int i = 0; i < 2; ++i)
    #pragma unroll
    for (int j = 0; j < 2; ++j)
      #pragma unroll
      for (int r = 0; r < 4; ++r){
        int p = wr + i*16 + g8*4 + r, n = wc + j*16 + r16;
        Tb[p*64 + n] = __float2bfloat16(acc[i][j][r]);
      }
  if (tid == 0) ctot[blockIdx.x] = expf(Lc);
}

// pass B: sequential state recurrence over chunks; bf16 storage, fp32 carry
__global__ __launch_bounds__(256) void k_scanB(bf16* __restrict__ T, const float* __restrict__ ctot)
{
  int h = blockIdx.x >> 3, e = blockIdx.x & 7;
  int tid = threadIdx.x;
  size_t off = (size_t)e * 512 + tid * 2;
  float s0 = 0.f, s1 = 0.f;
  for (int c0 = 0; c0 < 32; c0 += 8){
    ushort2 tv[8]; float cts[8];
    #pragma unroll
    for (int q = 0; q < 8; ++q){
      cts[q] = ctot[h * 32 + c0 + q];
      tv[q] = *(const ushort2*)&T[(size_t)(h * 32 + c0 + q) * 4096 + off];
    }
    #pragma unroll
    for (int q = 0; q < 8; ++q){
      size_t base = (size_t)(h * 32 + c0 + q) * 4096 + off;
      ushort2 sv; sv.x = bf16bits(s0); sv.y = bf16bits(s1);
      *(ushort2*)&T[base] = sv;
      s0 = fmaf(cts[q], s0, bfu(tv[q].x));
      s1 = fmaf(cts[q], s1, bfu(tv[q].y));
    }
  }
}

// ---- MFMA chunked-SSD pass C (bf16 everywhere) ----
__global__ __launch_bounds__(256) void k_scanC(
    const bf16* __restrict__ xbc, const bf16* __restrict__ Sin,
    const float* __restrict__ dtv, const float* __restrict__ lav,
    const float* __restrict__ Dp, bf16* __restrict__ y)
{
  __shared__ __bf16 sC[4096];
  __shared__ __bf16 sBS[4096];
  __shared__ __bf16 sXt[4096];
  __shared__ __bf16 sXr[4096];
  __shared__ __bf16 sSb[4096];
  __shared__ float scum[64], sdt[64];
  int h = blockIdx.x >> 5, c = blockIdx.x & 31;
  int tid = threadIdx.x, t0 = c * 64;
  if (tid < 64){
    float cum = lav[(size_t)(t0 + tid) * NHEADS + h];
    #pragma unroll
    for (int o = 1; o < 64; o <<= 1){
      float v = __shfl_up(cum, o, 64);
      if (tid >= o) cum += v;
    }
    scum[tid] = cum;
    sdt[tid] = dtv[(size_t)(t0 + tid) * NHEADS + h];
  }
  const bf16* Tb = Sin + (size_t)blockIdx.x * 4096;
  for (int idx = tid; idx < 512; idx += 256){
    int j = idx >> 3, n0 = (idx & 7) * 8;
    const bf16* rb = xbc + (size_t)(t0 + j) * CONVDIM;
    bf16x8 x8 = *(const bf16x8*)(rb + h * HEADDIM + n0);
    bf16x8 c8 = *(const bf16x8*)(rb + DINNER + DSTATE + n0);
    bf16x8 b8 = *(const bf16x8*)(rb + DINNER + n0);
    *(bf16x8*)(sC  + swz64(j, n0)) = c8;
    *(bf16x8*)(sBS + swz64(j, n0)) = b8;
    *(bf16x8*)(sXr + swz64(j, n0)) = x8;
    *(bf16x8*)(sSb + swz64(j, n0)) = *(const bf16x8*)(Tb + j*64 + n0);
    #pragma unroll
    for (int e = 0; e < 8; ++e)
      sXt[swz64(n0 + e, j)] = x8[e];
  }
  __syncthreads();
  int lane = tid & 63, wid = tid >> 6;
  int wr = (wid >> 1) * 32, wc = (wid & 1) * 32;
  int r16 = lane & 15, g8 = lane >> 4;
  f32x4 gacc[2][2];
  #pragma unroll
  for (int i = 0; i < 2; ++i)
    #pragma unroll
    for (int j = 0; j < 2; ++j) gacc[i][j] = (f32x4){0.f,0.f,0.f,0.f};
  #pragma unroll
  for (int kk = 0; kk < 2; ++kk){
    int ks = kk*4 + g8;
    bf16x8 a[2], b[2];
    #pragma unroll
    for (int i = 0; i < 2; ++i){
      int row = wr + i*16 + r16;
      a[i] = *(const bf16x8*)(sC + row*64 + ((ks ^ (row&7))<<3));
    }
    #pragma unroll
    for (int j = 0; j < 2; ++j){
      int row = wc + j*16 + r16;
      b[j] = *(const bf16x8*)(sBS + row*64 + ((ks ^ (row&7))<<3));
    }
    #pragma unroll
    for (int i = 0; i < 2; ++i)
      #pragma unroll
      for (int j = 0; j < 2; ++j)
        gacc[i][j] = __builtin_amdgcn_mfma_f32_16x16x32_bf16(a[i], b[j], gacc[i][j], 0, 0, 0);
  }
  __syncthreads();
  #pragma unroll
  for (int i = 0; i < 2; ++i)
    #pragma unroll
    for (int j = 0; j < 2; ++j)
      #pragma unroll
      for (int r = 0; r < 4; ++r){
        int i_ = wr + i*16 + g8*4 + r, j_ = wc + j*16 + r16;
        float v = (j_ <= i_) ? gacc[i][j][r] * expf(scum[i_] - scum[j_]) * sdt[j_] : 0.f;
        sBS[swz64(i_, j_)] = (__bf16)v;
      }
  __syncthreads();
  f32x4 a1[2][2], a2[2][2];
  #pragma unroll
  for (int i = 0; i < 2; ++i)
    #pragma unroll
    for (int j = 0; j < 2; ++j){
      a1[i][j] = (f32x4){0.f,0.f,0.f,0.f};
      a2[i][j] = (f32x4){0.f,0.f,0.f,0.f};
    }
  #pragma unroll
  for (int kk = 0; kk < 2; ++kk){
    int ks = kk*4 + g8;
    bf16x8 sa[2], xa[2], ca[2], sb[2];
    #pragma unroll
    for (int i = 0; i < 2; ++i){
      int row = wr + i*16 + r16;
      sa[i] = *(const bf16x8*)(sBS + row*64 + ((ks ^ (row&7))<<3));
      ca[i] = *(const bf16x8*)(sC  + row*64 + ((ks ^ (row&7))<<3));
    }
    #pragma unroll
    for (int j = 0; j < 2; ++j){
      int row = wc + j*16 + r16;
      xa[j] = *(const bf16x8*)(sXt + row*64 + ((ks ^ (row&7))<<3));
      sb[j] = *(const bf16x8*)(sSb + row*64 + ((ks ^ (row&7))<<3));
    }
    #pragma unroll
    for (int i = 0; i < 2; ++i)
      #pragma unroll
      for (int j = 0; j < 2; ++j){
        a1[i][j] = __builtin_amdgcn_mfma_f32_16x16x32_bf16(sa[i], xa[j], a1[i][j], 0, 0, 0);
        a2[i][j] = __builtin_amdgcn_mfma_f32_16x16x32_bf16(ca[i], sb[j], a2[i][j], 0, 0, 0);
      }
  }
  float Dh = Dp[h];
  #pragma unroll
  for (int i = 0; i < 2; ++i)
    #pragma unroll
    for (int r = 0; r < 4; ++r){
      int i_ = wr + i*16 + g8*4 + r;
      float wi = expf(scum[i_]);
      #pragma unroll
      for (int j = 0; j < 2; ++j){
        int p_ = wc + j*16 + r16;
        float xv = (float)sXr[swz64(i_, p_)];
        y[(size_t)(t0 + i_) * DINNER + h * HEADDIM + p_] =
            __float2bfloat16(a1[i][j][r] + wi * a2[i][j][r] + Dh * xv);
      }
    }
}

// yn = bf16(rms(y * silu(z)) * mnorm_w)   (y, z bf16)
__global__ __launch_bounds__(256) void k_gate_rms(
    const bf16* __restrict__ y, const bf16* __restrict__ zbuf,
    const float* __restrict__ mw, bf16* __restrict__ yn)
{
  int row = blockIdx.x, tid = threadIdx.x;
  bf16x8 yv = *(const bf16x8*)(y    + (size_t)row * DINNER + tid*8);
  bf16x8 zv = *(const bf16x8*)(zbuf + (size_t)row * DINNER + tid*8);
  float g[8]; float ss = 0.f;
  #pragma unroll
  for (int e = 0; e < 8; ++e){
    float gv = (float)yv[e] * siluf((float)zv[e]);
    g[e] = gv; ss += gv * gv;
  }
  ss = block_reduce_sum_256(ss);
  float inv = rsqrtf(ss / (float)DINNER + 1e-6f);
  float4 m0 = ((const float4*)mw)[tid*2];
  float4 m1 = ((const float4*)mw)[tid*2 + 1];
  const float* mp = (const float*)&m0;
  bf16x8 o;
  #pragma unroll
  for (int e = 0; e < 4; ++e) o[e] = (__bf16)(g[e] * inv * mp[e]);
  mp = (const float*)&m1;
  #pragma unroll
  for (int e = 0; e < 4; ++e) o[4+e] = (__bf16)(g[4+e] * inv * mp[e]);
  *(bf16x8*)(yn + (size_t)row * DINNER + tid*8) = o;
}

// x2 = xres + ssm_scale*(y0+y1+y2+y3) ; hb = bf16(rms(x2)*ffn_norm_w)  (yoP bf16)
__global__ __launch_bounds__(256) void k_res_rms(
    const float* __restrict__ xres, const bf16* __restrict__ yoP,
    const float* __restrict__ scale, const float* __restrict__ nw,
    float* __restrict__ x2, bf16* __restrict__ hb)
{
  int row = blockIdx.x, tid = threadIdx.x;
  const size_t PS = (size_t)LSEQ * DMODEL;
  float4 xv = ((const float4*)(xres + (size_t)row * DMODEL))[tid];
  ushort4 p0 = *(const ushort4*)(yoP          + (size_t)row * DMODEL + tid*4);
  ushort4 p1 = *(const ushort4*)(yoP +   PS   + (size_t)row * DMODEL + tid*4);
  ushort4 p2 = *(const ushort4*)(yoP + 2*PS   + (size_t)row * DMODEL + tid*4);
  ushort4 p3 = *(const ushort4*)(yoP + 3*PS   + (size_t)row * DMODEL + tid*4);
  float4 sv = ((const float4*)scale)[tid];
  float4 a;
  a.x = xv.x + sv.x*(bfu(p0.x)+bfu(p1.x)+bfu(p2.x)+bfu(p3.x));
  a.y = xv.y + sv.y*(bfu(p0.y)+bfu(p1.y)+bfu(p2.y)+bfu(p3.y));
  a.z = xv.z + sv.z*(bfu(p0.z)+bfu(p1.z)+bfu(p2.z)+bfu(p3.z));
  a.w = xv.w + sv.w*(bfu(p0.w)+bfu(p1.w)+bfu(p2.w)+bfu(p3.w));
  ((float4*)(x2 + (size_t)row * DMODEL))[tid] = a;
  float ss = a.x*a.x + a.y*a.y + a.z*a.z + a.w*a.w;
  ss = block_reduce_sum_256(ss);
  float inv = rsqrtf(ss / (float)DMODEL + 1e-6f);
  float4 nv = ((const float4*)nw)[tid];
  ushort4 o;
  o.x = bf16bits(a.x*inv*nv.x); o.y = bf16bits(a.y*inv*nv.y);
  o.z = bf16bits(a.z*inv*nv.z); o.w = bf16bits(a.w*inv*nv.w);
  *(ushort4*)(hb + (size_t)row * DMODEL + tid*4) = o;
}

// out = x2 + mscale*(d0+d1+d2+d3)   (dP bf16)
__global__ __launch_bounds__(256) void k_final(
    const float* __restrict__ x2, const bf16* __restrict__ dP,
    const float* __restrict__ mscale, float* __restrict__ out)
{
  int i4 = blockIdx.x * 256 + threadIdx.x;
  const size_t PS = (size_t)LSEQ * DMODEL;
  float4 xv = ((const float4*)x2)[i4];
  ushort4 p0 = *(const ushort4*)(dP        + (size_t)i4*4);
  ushort4 p1 = *(const ushort4*)(dP + PS   + (size_t)i4*4);
  ushort4 p2 = *(const ushort4*)(dP + 2*PS + (size_t)i4*4);
  ushort4 p3 = *(const ushort4*)(dP + 3*PS + (size_t)i4*4);
  float4 mv = ((const float4*)mscale)[i4 & 255];
  float4 o;
  o.x = xv.x + mv.x*(bfu(p0.x)+bfu(p1.x)+bfu(p2.x)+bfu(p3.x));
  o.y = xv.y + mv.y*(bfu(p0.y)+bfu(p1.y)+bfu(p2.y)+bfu(p3.y));
  o.z = xv.z + mv.z*(bfu(p0.z)+bfu(p1.z)+bfu(p2.z)+bfu(p3.z));
  o.w = xv.w + mv.w*(bfu(p0.w)+bfu(p1.w)+bfu(p2.w)+bfu(p3.w));
  ((float4*)out)[i4] = o;
}

extern "C" void kernel_launch(void* const* d_in, const int* in_sizes, int n_in,
                              void* d_out, int out_size, void* d_ws, size_t ws_size,
                              hipStream_t stream)
{
  const float* x      = (const float*)d_in[0];
  const float* x0     = (const float*)d_in[1];
  const float* rm     = (const float*)d_in[3];
  const float* sscale = (const float*)d_in[4];
  const float* mscale = (const float*)d_in[5];
  const float* snw    = (const float*)d_in[6];
  const float* fnw    = (const float*)d_in[7];
  const float* win    = (const float*)d_in[8];
  const float* cw     = (const float*)d_in[9];
  const float* cb     = (const float*)d_in[10];
  const float* dtb    = (const float*)d_in[11];
  const float* alog   = (const float*)d_in[12];
  const float* Dp     = (const float*)d_in[13];
  const float* mnw    = (const float*)d_in[14];
  const float* wout   = (const float*)d_in[15];
  const float* wgu    = (const float*)d_in[16];
  const float* wdn    = (const float*)d_in[17];
  float* out = (float*)d_out;

  // Workspace (MiB offsets), lifetime-overlapped (R13 layout):
  //  [0,4) woutb ; [4,16) wgub ; [16,22) wdnb ; [22,30) xres ; [30,39) winb
  //  [39,43) u bf16 -> dtv/lav -> hb bf16
  //  [43,51) zbuf bf16 (dead after gate_rms) -> x2 fp32
  //  [59,68) xbcdt bf16 -> yb bf16 [59,67) -> yoP bf16 [59,75) -> act bf16 [59,71)
  //  [71,87) dP bf16 ; [77,86) xbc bf16 (dead after scanC)
  //  [95,103) T/Sin bf16 -> yn bf16
  //  [112] ctot
  const size_t MB = 1024ull * 1024ull;
  char* ws = (char*)d_ws;
  bf16*  woutb = (bf16*) (ws + 0*MB);
  bf16*  wgub  = (bf16*) (ws + 4*MB);
  bf16*  wdnb  = (bf16*) (ws + 16*MB);
  float* xres  = (float*)(ws + 22*MB);
  bf16*  winb  = (bf16*) (ws + 30*MB);
  bf16*  u     = (bf16*) (ws + 39*MB);
  float* dtv   = (float*)(ws + 39*MB);
  float* lav   = (float*)(ws + 39*MB + 256*1024);
  bf16*  hb    = (bf16*) (ws + 39*MB);
  bf16*  zbuf  = (bf16*) (ws + 43*MB);
  float* x2    = (float*)(ws + 43*MB);
  bf16*  xbcdt = (bf16*) (ws + 59*MB);
  bf16*  yb    = (bf16*) (ws + 59*MB);
  bf16*  yoP   = (bf16*) (ws + 59*MB);
  bf16*  act   = (bf16*) (ws + 59*MB);
  bf16*  dP    = (bf16*) (ws + 71*MB);
  bf16*  xbc   = (bf16*) (ws + 77*MB);
  bf16*  T     = (bf16*) (ws + 95*MB);
  bf16*  yn    = (bf16*) (ws + 95*MB);
  float* ctot  = (float*)(ws + 112*MB);

  dim3 blk(256);
  k_castmix<<<17664, blk, 0, stream>>>(win, wout, wgu, wdn, winb, woutb, wgub, wdnb,
                                       x, x0, rm, snw, xres, u);
  k_gemm_inproj<<<dim3(34,16), blk, 0, stream>>>(u, winb, zbuf, xbcdt);
  k_convdt<<<(LSEQ*552)/256, blk, 0, stream>>>(xbcdt, cw, cb, dtb, alog, xbc, dtv, lav);
  k_scanA<<<NHEADS*32, blk, 0, stream>>>(xbc, dtv, lav, T, ctot);
  k_scanB<<<NHEADS*8, blk, 0, stream>>>(T, ctot);
  k_scanC<<<NHEADS*32, blk, 0, stream>>>(xbc, T, dtv, lav, Dp, yb);
  k_gate_rms<<<LSEQ, blk, 0, stream>>>(yb, zbuf, mnw, yn);
  k_gemm_splitk<<<dim3(8,16,4), blk, 0, stream>>>(yn, woutb, yoP, DINNER, DINNER/4, DMODEL);
  k_res_rms<<<LSEQ, blk, 0, stream>>>(xres, yoP, sscale, fnw, x2, hb);
  k_gemm_ffn<<<dim3(48,16), blk, 0, stream>>>(hb, wgub, wgub + (size_t)FFNHID*DMODEL, act, DMODEL);
  k_gemm_splitk<<<dim3(8,16,4), blk, 0, stream>>>(act, wdnb, dP, FFNHID, FFNHID/4, DMODEL);
  k_final<<<2048, blk, 0, stream>>>(x2, dP, mscale, out);
}